// Round 17
// baseline (623.450 us; speedup 1.0000x reference)
//
#include <hip/hip_runtime.h>
#include <stdint.h>

// ---------- common types / helpers ----------
typedef __attribute__((ext_vector_type(8))) __bf16 bf16x8;   // MFMA A/B frag (4 VGPR)
typedef __attribute__((ext_vector_type(4))) float  f32x4;    // MFMA C/D frag
typedef __attribute__((ext_vector_type(8))) unsigned short u16x8;
typedef __attribute__((ext_vector_type(2))) unsigned int u32x2;
typedef __attribute__((ext_vector_type(4))) unsigned int u32x4;

typedef __attribute__((address_space(1))) void AS1void;
typedef __attribute__((address_space(3))) void AS3void;
typedef __attribute__((address_space(3))) const unsigned char AS3c;

__device__ __forceinline__ float b2f(unsigned short u) {
  unsigned x = ((unsigned)u) << 16; float f; __builtin_memcpy(&f, &x, 4); return f;
}
__device__ __forceinline__ unsigned short f2b(float f) {
  unsigned x; __builtin_memcpy(&x, &f, 4);
  unsigned r = (x + 0x7fffu + ((x >> 16) & 1u)) >> 16;
  return (unsigned short)r;
}
// async global->LDS, 16B per lane; LDS dest must be wave-uniform base + lane*16
__device__ __forceinline__ void gload16(const void* g, void* l) {
  __builtin_amdgcn_global_load_lds((AS1void*)(void*)g, (AS3void*)l, 16, 0, 0);
}
__device__ __forceinline__ bf16x8 mk8(u32x2 a, u32x2 b) {
  u32x4 t; t[0] = a[0]; t[1] = a[1]; t[2] = b[0]; t[3] = b[1];
  bf16x8 r; __builtin_memcpy(&r, &t, 16); return r;
}
// ds_read_b64_tr_b16: HW 4x16 bf16 transpose within each 16-lane group [m156/m162].
template<int OFF>
__device__ __forceinline__ u32x2 tr_read(AS3c* vp) {
  u32x2 r;
  asm volatile("ds_read_b64_tr_b16 %0, %1 offset:%2"
               : "=&v"(r) : "v"(vp), "n"(OFF));
  return r;
}

// ---------- elementwise cast f32 -> bf16 ----------
__global__ __launch_bounds__(256) void k_cast(const float* __restrict__ in,
                                              unsigned short* __restrict__ out, long n) {
  long i = ((long)blockIdx.x * 256 + threadIdx.x) * 4;
  if (i >= n) return;
  float4 v = *(const float4*)(in + i);
  ushort4 o;
  o.x = f2b(v.x); o.y = f2b(v.y); o.z = f2b(v.z); o.w = f2b(v.w);
  *(ushort4*)(out + i) = o;
}

// ---------- wkv_b prep ----------
__global__ __launch_bounds__(256) void k_prep_wkvb(const float* __restrict__ wkvb,
                                                   unsigned short* __restrict__ kT,
                                                   unsigned short* __restrict__ vv) {
  long i = (long)blockIdx.x * 256 + threadIdx.x;   // < 16*512*128 = 1048576
  {
    int d = (int)(i & 127); long r = i >> 7; int c = (int)(r & 511); int h = (int)(r >> 9);
    kT[i] = f2b(wkvb[((long)(h * 256 + d)) * 512 + c]);
  }
  {
    int c = (int)(i & 511); long r = i >> 9; int d = (int)(r & 127); int h = (int)(r >> 7);
    vv[i] = f2b(wkvb[((long)(h * 256 + 128 + d)) * 512 + c]);
  }
}

// ---------- generic BT-form GEMM: C[M,N] = A[M,K] @ B[N,K]^T (+bias) ----------
// Bijective XCD swizzle (m204) on the xy grid for per-XCD L2 weight locality.
template<int OUTF32, int BIAS>
__global__ __launch_bounds__(256, 4) void k_gemm_bt(
    const unsigned short* __restrict__ A, long lda, long aSb, long aSh,
    const unsigned short* __restrict__ B, long ldb, long bSb, long bSh,
    void* __restrict__ Cp, long ldc, long cSb, long cSh,
    const float* __restrict__ bias,
    int M, int N, int K, int zH) {
  __shared__ __align__(16) unsigned short sA[128 * 32];
  __shared__ __align__(16) unsigned short sB[128 * 32];
  const int z = blockIdx.z, zb = z / zH, zh = z % zH;
  const unsigned short* Ab = A + zb * aSb + zh * aSh;
  const unsigned short* Bb = B + zb * bSb + zh * bSh;
  const long cOff = (long)zb * cSb + (long)zh * cSh;
  const int nwg = gridDim.x * gridDim.y;
  int flat = blockIdx.y * gridDim.x + blockIdx.x;
  {
    int q = nwg >> 3, r = nwg & 7;
    int xcd = flat & 7, j = flat >> 3;
    flat = (xcd < r ? xcd * (q + 1) : r * (q + 1) + (xcd - r) * q) + j;
  }
  const int n0 = (flat % gridDim.x) * 128, m0 = (flat / gridDim.x) * 128;
  const int t = threadIdx.x, w = t >> 6, l = t & 63;
  const int wr = (w >> 1) * 64, wc = (w & 1) * 64;
  const int lr = l & 15, lg = l >> 4;
  f32x4 acc[4][4] = {};
  for (int k0 = 0; k0 < K; k0 += 32) {
    #pragma unroll
    for (int cc = 0; cc < 2; ++cc) {
      int c = t + cc * 256;
      int row = c >> 2, col = (c & 3) * 8;
      int ar = m0 + row; ar = ar < M ? ar : M - 1;
      int br = n0 + row; br = br < N ? br : N - 1;
      gload16(Ab + (long)ar * lda + k0 + col, (char*)sA + c * 16);
      gload16(Bb + (long)br * ldb + k0 + col, (char*)sB + c * 16);
    }
    __syncthreads();
    bf16x8 af[4], bf[4];
    #pragma unroll
    for (int i = 0; i < 4; ++i) af[i] = *(const bf16x8*)&sA[(wr + i * 16 + lr) * 32 + lg * 8];
    #pragma unroll
    for (int j = 0; j < 4; ++j) bf[j] = *(const bf16x8*)&sB[(wc + j * 16 + lr) * 32 + lg * 8];
    #pragma unroll
    for (int i = 0; i < 4; ++i)
      #pragma unroll
      for (int j = 0; j < 4; ++j)
        acc[i][j] = __builtin_amdgcn_mfma_f32_16x16x32_bf16(af[i], bf[j], acc[i][j], 0, 0, 0);
    __syncthreads();
  }
  #pragma unroll
  for (int i = 0; i < 4; ++i) {
    #pragma unroll
    for (int r = 0; r < 4; ++r) {
      int row = m0 + wr + i * 16 + lg * 4 + r;
      if (row >= M) continue;
      #pragma unroll
      for (int j = 0; j < 4; ++j) {
        int col = n0 + wc + j * 16 + lr;
        if (col >= N) continue;
        float v = acc[i][j][r];
        if (BIAS) v += bias[col];
        if (OUTF32) ((float*)Cp)[cOff + (long)row * ldc + col] = v;
        else ((unsigned short*)Cp)[cOff + (long)row * ldc + col] = f2b(v);
      }
    }
  }
}

// ---------- fused LayerNorm (cols 0..511) + RoPE k_pe (cols 512..575) ----------
__global__ __launch_bounds__(256) void k_ln_rope(const unsigned short* __restrict__ kvb,
                                                 const float* __restrict__ g,
                                                 const float* __restrict__ be,
                                                 const float* __restrict__ fc,
                                                 const float* __restrict__ fs,
                                                 unsigned short* __restrict__ kcat) {
  const int w = threadIdx.x >> 6, l = threadIdx.x & 63;
  const long row = (long)blockIdx.x * 4 + w;       // 0..4095
  const unsigned short* src = kvb + row * 576 + l * 8;
  u16x8 v = *(const u16x8*)src;
  float f[8]; float s = 0.f, s2 = 0.f;
  #pragma unroll
  for (int j = 0; j < 8; ++j) { f[j] = b2f(v[j]); s += f[j]; s2 += f[j] * f[j]; }
  #pragma unroll
  for (int m = 1; m < 64; m <<= 1) { s += __shfl_xor(s, m); s2 += __shfl_xor(s2, m); }
  float mu = s * (1.f / 512.f);
  float var = s2 * (1.f / 512.f) - mu * mu;
  float rs = rsqrtf(var + 1e-5f);
  u16x8 o;
  #pragma unroll
  for (int j = 0; j < 8; ++j) {
    int c = l * 8 + j;
    o[j] = f2b((f[j] - mu) * rs * g[c] + be[c]);
  }
  *(u16x8*)(kcat + row * 576 + l * 8) = o;
  if (l < 32) {
    int p = l;
    int sidx = (int)(row & 2047);
    long base = row * 576 + 512 + 2 * p;
    float re = b2f(kvb[base]), im = b2f(kvb[base + 1]);
    float c = fc[sidx * 32 + p], sn = fs[sidx * 32 + p];
    kcat[base] = f2b(re * c - im * sn);
    kcat[base + 1] = f2b(re * sn + im * c);
  }
}

// ---------- RoPE for q_pe (grid 8192: one pair per thread) ----------
__global__ __launch_bounds__(256) void k_rope_q(const unsigned short* __restrict__ qfull,
                                                const float* __restrict__ fc,
                                                const float* __restrict__ fs,
                                                unsigned short* __restrict__ qcat) {
  long i = (long)blockIdx.x * 256 + threadIdx.x;  // < 2*2048*16*32 = 2097152
  int p = (int)(i & 31); long r = i >> 5;
  int h = (int)(r & 15); r >>= 4;
  int s = (int)(r & 2047); int b = (int)(r >> 11);
  const unsigned short* src = qfull + ((long)(b * 2048 + s)) * 3072 + h * 192 + 128 + 2 * p;
  float re = b2f(src[0]), im = b2f(src[1]);
  float c = fc[s * 32 + p], sn = fs[s * 32 + p];
  unsigned short* dst = qcat + ((long)((b * 16 + h) * 2048 + s)) * 576 + 512 + 2 * p;
  dst[0] = f2b(re * c - im * sn);
  dst[1] = f2b(re * sn + im * c);
}

// ---------- flash attention (Design H17: H13 + 4-way QK chain split, (256,2) kept) ----------
// K tile [32 t][576 c] SUBTILED in LDS (sub=(c>>4)*8+(t>>2), elem (t&3)*16+(c&15));
// one copy serves QK A-frags (16B reads) AND PV V^T frags (ds_read_b64_tr_b16).
// Double-buffered; 2 barriers/tile. QK accumulators split into 4 independent 9-deep
// MFMA chains (scA/scB per tf) to halve the QK latency-chain; halves summed at mask.
// 78KB LDS, (256,2): 128 arch VGPR + 128 acc AGPR = 256/wave -> 2 blocks/CU ceiling.
__global__ __launch_bounds__(256, 2) void k_attn(
    const unsigned short* __restrict__ qcat,   // [B*H][2048][576]
    const unsigned short* __restrict__ kcat,   // [B][2048][576]
    unsigned short* __restrict__ ctx,          // [B*H][2048][512]
    const int* __restrict__ spp) {
  __shared__ __align__(16) char smem[78336];
  // [0,73728) sK dbuf | [73728,77824) sP | [77824,78080) sAl | [78080,78096) sNeed
  const int id = blockIdx.x;
  const int rr = id & 7;                       // XCD slot (HW round-robins id%8)
  const int b = rr >> 2;                       // b=0 -> XCD 0-3, b=1 -> XCD 4-7
  const int local = (id >> 3) * 4 + (rr & 3);  // 0..511 within batch class
  const int qb = 31 - (local >> 4);            // LPT: largest blocks first
  const int h = local & 15;
  const int t = threadIdx.x, w = t >> 6, l = t & 63;
  const int lq = l & 15, hh = l >> 4;
  const int sp = spp[0];
  const long bh = (long)(b * 16 + h);
  const long qrow0 = bh * 2048 + qb * 64 + w * 16;
  const float scale = 0.07216878364870323f;    // 1/sqrt(192)

  // Q resident in B-frag layout
  bf16x8 qf[18];
  #pragma unroll
  for (int kk = 0; kk < 18; ++kk)
    qf[kk] = *(const bf16x8*)&qcat[(qrow0 + lq) * 576 + kk * 32 + hh * 8];

  f32x4 acc[8][4];   // D[c][q]: c = w*128 + cb*16 + 4*hh + r ; q = q2*16 + lq
  #pragma unroll
  for (int i = 0; i < 8; ++i)
    #pragma unroll
    for (int j = 0; j < 4; ++j) acc[i][j] = (f32x4){0.f, 0.f, 0.f, 0.f};
  float mrun = -1e30f, lrun = 0.f;
  const int qg = qb * 64 + w * 16 + lq + sp;
  int tmax = qb * 64 + 63 + sp; if (tmax > 2047) tmax = 2047;

  const unsigned short* kbase = kcat + (long)b * 2048 * 576;

  // stage K tile t0 into buffer bi, subtiled layout; chunk c (16B) -> LDS linear c*16
  auto STAGE = [&](int bi, int t0) {
    char* dK = smem + bi * 36864;
    #pragma unroll
    for (int cc = 0; cc < 9; ++cc) {
      int c = t + cc * 256;                    // 0..2303
      int tt = ((c >> 3) & 7) * 4 + ((c >> 1) & 3);
      int gc = (c >> 6) * 16 + (c & 1) * 8;
      gload16(kbase + (long)(t0 + tt) * 576 + gc, dK + c * 16);
    }
  };

  STAGE(0, 0);
  int cur = 0;
  unsigned short* sP = (unsigned short*)(smem + 73728);
  float* sAl = (float*)(smem + 77824);
  int* sNeed = (int*)(smem + 78080);
  const int qrow = w * 16 + lq;                // block-local q (0..63)
  const int xq = ((qrow >> 1) & 3) << 4;
  const int vcol = (hh * 16) ^ (((lq >> 1) & 3) << 4);   // sP read col
  // QK per-lane base byte offset within K tile (subtiled addressing)
  const int kq = ((lq >> 2) << 7) + ((lq & 3) << 5) + ((hh & 1) << 4) + ((hh >> 1) << 10);

  for (int t0 = 0; t0 <= tmax; t0 += 32) {
    // stage(t0) was issued during PV of the previous tile (or pre-loop) -> drain
    asm volatile("s_waitcnt vmcnt(0)" ::: "memory");
    __builtin_amdgcn_sched_barrier(0);
    __builtin_amdgcn_s_barrier();              // A: buffer `cur` staged; prev reads done
    __builtin_amdgcn_sched_barrier(0);

    // ---- QK^T (swapped): scores^T[t][q]; 4 independent 9-deep chains
    const char* sKc = smem + cur * 36864;
    f32x4 scA[2], scB[2];
    scA[0] = (f32x4){0.f,0.f,0.f,0.f}; scA[1] = (f32x4){0.f,0.f,0.f,0.f};
    scB[0] = (f32x4){0.f,0.f,0.f,0.f}; scB[1] = (f32x4){0.f,0.f,0.f,0.f};
    __builtin_amdgcn_s_setprio(1);
    #pragma unroll
    for (int tf = 0; tf < 2; ++tf) {
      const char* rb = sKc + kq + tf * 512;
      #pragma unroll
      for (int kk = 0; kk < 9; ++kk) {
        bf16x8 kfA = *(const bf16x8*)(rb + kk * 2048);
        scA[tf] = __builtin_amdgcn_mfma_f32_16x16x32_bf16(kfA, qf[kk], scA[tf], 0, 0, 0);
        bf16x8 kfB = *(const bf16x8*)(rb + (kk + 9) * 2048);
        scB[tf] = __builtin_amdgcn_mfma_f32_16x16x32_bf16(kfB, qf[kk + 9], scB[tf], 0, 0, 0);
      }
    }
    __builtin_amdgcn_s_setprio(0);

    // ---- softmax (lane-local per q) with defer-max
    float v[2][4];
    float mt = -1e30f;
    #pragma unroll
    for (int tf = 0; tf < 2; ++tf)
      #pragma unroll
      for (int r = 0; r < 4; ++r) {
        int tg = t0 + tf * 16 + 4 * hh + r;
        v[tf][r] = (tg <= qg) ? (scA[tf][r] + scB[tf][r]) * scale : -1e30f;
        mt = fmaxf(mt, v[tf][r]);
      }
    mt = fmaxf(mt, __shfl_xor(mt, 16));
    mt = fmaxf(mt, __shfl_xor(mt, 32));
    float al = 1.f;
    unsigned long long needb = __ballot(mt > mrun + 8.f);
    if (needb) {
      float mn = fmaxf(mrun, mt);
      al = __expf(mrun - mn);
      mrun = mn;
      lrun *= al;
    }
    float sr = 0.f;
    #pragma unroll
    for (int tf = 0; tf < 2; ++tf) {
      ushort4 pk;
      float e0 = __expf(v[tf][0] - mrun);
      float e1 = __expf(v[tf][1] - mrun);
      float e2 = __expf(v[tf][2] - mrun);
      float e3 = __expf(v[tf][3] - mrun);
      sr += (e0 + e1) + (e2 + e3);
      pk.x = f2b(e0); pk.y = f2b(e1); pk.z = f2b(e2); pk.w = f2b(e3);
      *(ushort4*)((char*)sP + qrow * 64 + ((32 * tf + 8 * hh) ^ xq)) = pk;
    }
    sr += __shfl_xor(sr, 16);
    sr += __shfl_xor(sr, 32);
    lrun += sr;
    if (l < 16) sAl[w * 16 + l] = al;
    if (l == 0) sNeed[w] = needb ? 1 : 0;
    asm volatile("s_waitcnt lgkmcnt(0)" ::: "memory");
    __builtin_amdgcn_sched_barrier(0);
    __builtin_amdgcn_s_barrier();              // B: sP / sAl / sNeed visible
    __builtin_amdgcn_sched_barrier(0);

    // ---- issue next-tile prefetch NOW (flies during PV); safe per barrier A
    if (t0 + 32 <= tmax) STAGE(cur ^ 1, t0 + 32);
    __builtin_amdgcn_sched_barrier(0);

    // ---- rescale (block-uniform, usually skipped) + PV via tr-reads
    int needAny = sNeed[0] | sNeed[1] | sNeed[2] | sNeed[3];
    if (needAny) {
      float a4[4];
      #pragma unroll
      for (int q2 = 0; q2 < 4; ++q2) a4[q2] = sAl[q2 * 16 + lq];
      #pragma unroll
      for (int cb = 0; cb < 8; ++cb)
        #pragma unroll
        for (int q2 = 0; q2 < 4; ++q2) acc[cb][q2] *= a4[q2];
    }
    bf16x8 pf0 = *(const bf16x8*)((char*)sP + (0 * 16 + lq) * 64 + vcol);
    bf16x8 pf1 = *(const bf16x8*)((char*)sP + (1 * 16 + lq) * 64 + vcol);
    bf16x8 pf2 = *(const bf16x8*)((char*)sP + (2 * 16 + lq) * 64 + vcol);
    bf16x8 pf3 = *(const bf16x8*)((char*)sP + (3 * 16 + lq) * 64 + vcol);
    __builtin_amdgcn_sched_barrier(0);         // pin pf issue before tr-reads (count!)
    AS3c* vp3 = (AS3c*)(smem + cur * 36864 + (w * 8192) + hh * 256 + lq * 8);
    u32x2 A0, A1, B0, B1, C0, C1, D0, D1;
    #define TRR2(d0, d1, CB) do { \
      d0 = tr_read<(CB) * 1024>(vp3); \
      d1 = tr_read<(CB) * 1024 + 128>(vp3); } while (0)
    #define PVC(CB, E0, E1) do { \
      bf16x8 vf = mk8(E0, E1); \
      acc[CB][0] = __builtin_amdgcn_mfma_f32_16x16x32_bf16(vf, pf0, acc[CB][0], 0, 0, 0); \
      acc[CB][1] = __builtin_amdgcn_mfma_f32_16x16x32_bf16(vf, pf1, acc[CB][1], 0, 0, 0); \
      acc[CB][2] = __builtin_amdgcn_mfma_f32_16x16x32_bf16(vf, pf2, acc[CB][2], 0, 0, 0); \
      acc[CB][3] = __builtin_amdgcn_mfma_f32_16x16x32_bf16(vf, pf3, acc[CB][3], 0, 0, 0); } while (0)
    TRR2(A0, A1, 0); TRR2(B0, B1, 1);
    TRR2(C0, C1, 2); TRR2(D0, D1, 3);
    asm volatile("s_waitcnt lgkmcnt(4)" ::: "memory");   // pf + cb0,1 ready
    __builtin_amdgcn_sched_barrier(0);
    __builtin_amdgcn_s_setprio(1);
    PVC(0, A0, A1); PVC(1, B0, B1);
    __builtin_amdgcn_s_setprio(0);
    TRR2(A0, A1, 4); TRR2(B0, B1, 5);
    asm volatile("s_waitcnt lgkmcnt(4)" ::: "memory");   // cb2,3 ready
    __builtin_amdgcn_sched_barrier(0);
    __builtin_amdgcn_s_setprio(1);
    PVC(2, C0, C1); PVC(3, D0, D1);
    __builtin_amdgcn_s_setprio(0);
    TRR2(C0, C1, 6); TRR2(D0, D1, 7);
    asm volatile("s_waitcnt lgkmcnt(4)" ::: "memory");   // cb4,5 ready
    __builtin_amdgcn_sched_barrier(0);
    __builtin_amdgcn_s_setprio(1);
    PVC(4, A0, A1); PVC(5, B0, B1);
    __builtin_amdgcn_s_setprio(0);
    asm volatile("s_waitcnt lgkmcnt(0)" ::: "memory");   // cb6,7 ready
    __builtin_amdgcn_sched_barrier(0);
    __builtin_amdgcn_s_setprio(1);
    PVC(6, C0, C1); PVC(7, D0, D1);
    __builtin_amdgcn_s_setprio(0);
    #undef TRR2
    #undef PVC
    __builtin_amdgcn_sched_barrier(0);
    cur ^= 1;
  }

  // ---- epilogue: 1/l scaling + LDS transpose to coalesced ctx store
  if (l < 16) sAl[w * 16 + l] = lrun;
  __syncthreads();
  float linv[4];
  #pragma unroll
  for (int q2 = 0; q2 < 4; ++q2) linv[q2] = 1.0f / sAl[q2 * 16 + lq];
  unsigned short* eb = (unsigned short*)smem;   // [64 q][528]
  #pragma unroll
  for (int cb = 0; cb < 8; ++cb) {
    const int c0 = w * 128 + cb * 16 + hh * 4;
    #pragma unroll
    for (int q2 = 0; q2 < 4; ++q2) {
      f32x4 a = acc[cb][q2];
      ushort4 o;
      o.x = f2b(a[0] * linv[q2]); o.y = f2b(a[1] * linv[q2]);
      o.z = f2b(a[2] * linv[q2]); o.w = f2b(a[3] * linv[q2]);
      *(ushort4*)&eb[(q2 * 16 + lq) * 528 + c0] = o;
    }
  }
  __syncthreads();
  unsigned short* Co = ctx + (bh * 2048 + qb * 64) * 512;
  #pragma unroll
  for (int i = 0; i < 16; ++i) {
    int id2 = t + i * 256;                     // 0..4095 chunks of 8 elems
    int row = id2 >> 6, col = (id2 & 63) * 8;
    *(u16x8*)&Co[(long)row * 512 + col] = *(const u16x8*)&eb[row * 528 + col];
  }
}

// ---------- host launch ----------
extern "C" void kernel_launch(void* const* d_in, const int* in_sizes, int n_in,
                              void* d_out, int out_size, void* d_ws, size_t ws_size,
                              hipStream_t stream) {
  const float* x      = (const float*)d_in[0];
  const int*   sp     = (const int*)d_in[1];
  const float* fcos   = (const float*)d_in[2];
  const float* fsin   = (const float*)d_in[3];
  const float* wq_w   = (const float*)d_in[4];
  const float* wq_b   = (const float*)d_in[5];
  const float* wkva_w = (const float*)d_in[6];
  const float* wkva_b = (const float*)d_in[7];
  const float* lng    = (const float*)d_in[8];
  const float* lnb    = (const float*)d_in[9];
  const float* wkvb_w = (const float*)d_in[10];
  const float* wo_w   = (const float*)d_in[11];
  const float* wo_b   = (const float*)d_in[12];
  float* out = (float*)d_out;

  if (ws_size < 171180032) return;

  char* ws = (char*)d_ws;
  unsigned short* xb     = (unsigned short*)(ws + 0);
  unsigned short* wqbf   = (unsigned short*)(ws + 16777216);
  unsigned short* qfull  = (unsigned short*)(ws + 29360128);
  unsigned short* ctx    = (unsigned short*)(ws + 0);
  unsigned short* wkvabf = (unsigned short*)(ws + 67108864);
  unsigned short* wkvbkT = (unsigned short*)(ws + 69468160);
  unsigned short* wkvbv  = (unsigned short*)(ws + 71565312);
  unsigned short* wobf   = (unsigned short*)(ws + 73662464);
  unsigned short* kvbf   = (unsigned short*)(ws + 82051072);
  unsigned short* kcat   = (unsigned short*)(ws + 86769664);
  unsigned short* qcat   = (unsigned short*)(ws + 95682560);
  unsigned short* outh   = qcat;

  k_cast<<<8192, 256, 0, stream>>>(x, xb, 8388608L);
  k_cast<<<6144, 256, 0, stream>>>(wq_w, wqbf, 6291456L);
  k_cast<<<1152, 256, 0, stream>>>(wkva_w, wkvabf, 1179648L);
  k_cast<<<4096, 256, 0, stream>>>(wo_w, wobf, 4194304L);
  k_prep_wkvb<<<4096, 256, 0, stream>>>(wkvb_w, wkvbkT, wkvbv);

  k_gemm_bt<0, 1><<<dim3(24, 32, 1), 256, 0, stream>>>(
      xb, 2048, 0, 0, wqbf, 2048, 0, 0, qfull, 3072, 0, 0, wq_b, 4096, 3072, 2048, 1);
  k_gemm_bt<0, 1><<<dim3(5, 32, 1), 256, 0, stream>>>(
      xb, 2048, 0, 0, wkvabf, 2048, 0, 0, kvbf, 576, 0, 0, wkva_b, 4096, 576, 2048, 1);

  k_ln_rope<<<1024, 256, 0, stream>>>(kvbf, lng, lnb, fcos, fsin, kcat);
  k_rope_q<<<8192, 256, 0, stream>>>(qfull, fcos, fsin, qcat);

  k_gemm_bt<0, 0><<<dim3(4, 16, 32), 256, 0, stream>>>(
      qfull, 3072, (long)2048 * 3072, 192,
      wkvbkT, 128, 0, (long)512 * 128,
      qcat, 576, (long)16 * 2048 * 576, (long)2048 * 576,
      nullptr, 2048, 512, 128, 16);

  k_attn<<<dim3(1024, 1, 1), 256, 0, stream>>>(qcat, kcat, ctx, sp);

  k_gemm_bt<0, 0><<<dim3(1, 16, 32), 256, 0, stream>>>(
      ctx, 512, (long)16 * 2048 * 512, (long)2048 * 512,
      wkvbv, 512, 0, (long)128 * 512,
      outh, 2048, (long)2048 * 2048, 128,
      nullptr, 2048, 128, 512, 16);

  k_gemm_bt<1, 1><<<dim3(16, 32, 1), 256, 0, stream>>>(
      outh, 2048, 0, 0, wobf, 2048, 0, 0, out, 2048, 0, 0, wo_b, 4096, 2048, 2048, 1);
}

// Round 18
// 605.722 us; speedup vs baseline: 1.0293x; 1.0293x over previous
//
#include <hip/hip_runtime.h>
#include <stdint.h>

// ---------- common types / helpers ----------
typedef __attribute__((ext_vector_type(8))) __bf16 bf16x8;   // MFMA A/B frag (4 VGPR)
typedef __attribute__((ext_vector_type(4))) float  f32x4;    // MFMA C/D frag
typedef __attribute__((ext_vector_type(8))) unsigned short u16x8;
typedef __attribute__((ext_vector_type(2))) unsigned int u32x2;
typedef __attribute__((ext_vector_type(4))) unsigned int u32x4;

typedef __attribute__((address_space(1))) void AS1void;
typedef __attribute__((address_space(3))) void AS3void;
typedef __attribute__((address_space(3))) const unsigned char AS3c;

__device__ __forceinline__ float b2f(unsigned short u) {
  unsigned x = ((unsigned)u) << 16; float f; __builtin_memcpy(&f, &x, 4); return f;
}
__device__ __forceinline__ unsigned short f2b(float f) {
  unsigned x; __builtin_memcpy(&x, &f, 4);
  unsigned r = (x + 0x7fffu + ((x >> 16) & 1u)) >> 16;
  return (unsigned short)r;
}
// async global->LDS, 16B per lane; LDS dest must be wave-uniform base + lane*16
__device__ __forceinline__ void gload16(const void* g, void* l) {
  __builtin_amdgcn_global_load_lds((AS1void*)(void*)g, (AS3void*)l, 16, 0, 0);
}
__device__ __forceinline__ bf16x8 mk8(u32x2 a, u32x2 b) {
  u32x4 t; t[0] = a[0]; t[1] = a[1]; t[2] = b[0]; t[3] = b[1];
  bf16x8 r; __builtin_memcpy(&r, &t, 16); return r;
}
// ds_read_b64_tr_b16: HW 4x16 bf16 transpose within each 16-lane group [m156/m162].
template<int OFF>
__device__ __forceinline__ u32x2 tr_read(AS3c* vp) {
  u32x2 r;
  asm volatile("ds_read_b64_tr_b16 %0, %1 offset:%2"
               : "=&v"(r) : "v"(vp), "n"(OFF));
  return r;
}

// ---------- elementwise cast f32 -> bf16 ----------
__global__ __launch_bounds__(256) void k_cast(const float* __restrict__ in,
                                              unsigned short* __restrict__ out, long n) {
  long i = ((long)blockIdx.x * 256 + threadIdx.x) * 4;
  if (i >= n) return;
  float4 v = *(const float4*)(in + i);
  ushort4 o;
  o.x = f2b(v.x); o.y = f2b(v.y); o.z = f2b(v.z); o.w = f2b(v.w);
  *(ushort4*)(out + i) = o;
}

// ---------- wkv_b prep ----------
__global__ __launch_bounds__(256) void k_prep_wkvb(const float* __restrict__ wkvb,
                                                   unsigned short* __restrict__ kT,
                                                   unsigned short* __restrict__ vv) {
  long i = (long)blockIdx.x * 256 + threadIdx.x;   // < 16*512*128 = 1048576
  {
    int d = (int)(i & 127); long r = i >> 7; int c = (int)(r & 511); int h = (int)(r >> 9);
    kT[i] = f2b(wkvb[((long)(h * 256 + d)) * 512 + c]);
  }
  {
    int c = (int)(i & 511); long r = i >> 9; int d = (int)(r & 127); int h = (int)(r >> 7);
    vv[i] = f2b(wkvb[((long)(h * 256 + 128 + d)) * 512 + c]);
  }
}

// ---------- generic BT-form GEMM: C[M,N] = A[M,K] @ B[N,K]^T (+bias) ----------
// Bijective XCD swizzle (m204) on the xy grid for per-XCD L2 weight locality.
// Single-buffered (TLP at 4 blocks/CU already hides staging; dbuf was neutral-negative).
template<int OUTF32, int BIAS>
__global__ __launch_bounds__(256, 4) void k_gemm_bt(
    const unsigned short* __restrict__ A, long lda, long aSb, long aSh,
    const unsigned short* __restrict__ B, long ldb, long bSb, long bSh,
    void* __restrict__ Cp, long ldc, long cSb, long cSh,
    const float* __restrict__ bias,
    int M, int N, int K, int zH) {
  __shared__ __align__(16) unsigned short sA[128 * 32];
  __shared__ __align__(16) unsigned short sB[128 * 32];
  const int z = blockIdx.z, zb = z / zH, zh = z % zH;
  const unsigned short* Ab = A + zb * aSb + zh * aSh;
  const unsigned short* Bb = B + zb * bSb + zh * bSh;
  const long cOff = (long)zb * cSb + (long)zh * cSh;
  const int nwg = gridDim.x * gridDim.y;
  int flat = blockIdx.y * gridDim.x + blockIdx.x;
  {
    int q = nwg >> 3, r = nwg & 7;
    int xcd = flat & 7, j = flat >> 3;
    flat = (xcd < r ? xcd * (q + 1) : r * (q + 1) + (xcd - r) * q) + j;
  }
  const int n0 = (flat % gridDim.x) * 128, m0 = (flat / gridDim.x) * 128;
  const int t = threadIdx.x, w = t >> 6, l = t & 63;
  const int wr = (w >> 1) * 64, wc = (w & 1) * 64;
  const int lr = l & 15, lg = l >> 4;
  f32x4 acc[4][4] = {};
  for (int k0 = 0; k0 < K; k0 += 32) {
    #pragma unroll
    for (int cc = 0; cc < 2; ++cc) {
      int c = t + cc * 256;
      int row = c >> 2, col = (c & 3) * 8;
      int ar = m0 + row; ar = ar < M ? ar : M - 1;
      int br = n0 + row; br = br < N ? br : N - 1;
      gload16(Ab + (long)ar * lda + k0 + col, (char*)sA + c * 16);
      gload16(Bb + (long)br * ldb + k0 + col, (char*)sB + c * 16);
    }
    __syncthreads();
    bf16x8 af[4], bf[4];
    #pragma unroll
    for (int i = 0; i < 4; ++i) af[i] = *(const bf16x8*)&sA[(wr + i * 16 + lr) * 32 + lg * 8];
    #pragma unroll
    for (int j = 0; j < 4; ++j) bf[j] = *(const bf16x8*)&sB[(wc + j * 16 + lr) * 32 + lg * 8];
    #pragma unroll
    for (int i = 0; i < 4; ++i)
      #pragma unroll
      for (int j = 0; j < 4; ++j)
        acc[i][j] = __builtin_amdgcn_mfma_f32_16x16x32_bf16(af[i], bf[j], acc[i][j], 0, 0, 0);
    __syncthreads();
  }
  #pragma unroll
  for (int i = 0; i < 4; ++i) {
    #pragma unroll
    for (int r = 0; r < 4; ++r) {
      int row = m0 + wr + i * 16 + lg * 4 + r;
      if (row >= M) continue;
      #pragma unroll
      for (int j = 0; j < 4; ++j) {
        int col = n0 + wc + j * 16 + lr;
        if (col >= N) continue;
        float v = acc[i][j][r];
        if (BIAS) v += bias[col];
        if (OUTF32) ((float*)Cp)[cOff + (long)row * ldc + col] = v;
        else ((unsigned short*)Cp)[cOff + (long)row * ldc + col] = f2b(v);
      }
    }
  }
}

// ---------- fused LayerNorm (cols 0..511) + RoPE k_pe (cols 512..575) ----------
__global__ __launch_bounds__(256) void k_ln_rope(const unsigned short* __restrict__ kvb,
                                                 const float* __restrict__ g,
                                                 const float* __restrict__ be,
                                                 const float* __restrict__ fc,
                                                 const float* __restrict__ fs,
                                                 unsigned short* __restrict__ kcat) {
  const int w = threadIdx.x >> 6, l = threadIdx.x & 63;
  const long row = (long)blockIdx.x * 4 + w;       // 0..4095
  const unsigned short* src = kvb + row * 576 + l * 8;
  u16x8 v = *(const u16x8*)src;
  float f[8]; float s = 0.f, s2 = 0.f;
  #pragma unroll
  for (int j = 0; j < 8; ++j) { f[j] = b2f(v[j]); s += f[j]; s2 += f[j] * f[j]; }
  #pragma unroll
  for (int m = 1; m < 64; m <<= 1) { s += __shfl_xor(s, m); s2 += __shfl_xor(s2, m); }
  float mu = s * (1.f / 512.f);
  float var = s2 * (1.f / 512.f) - mu * mu;
  float rs = rsqrtf(var + 1e-5f);
  u16x8 o;
  #pragma unroll
  for (int j = 0; j < 8; ++j) {
    int c = l * 8 + j;
    o[j] = f2b((f[j] - mu) * rs * g[c] + be[c]);
  }
  *(u16x8*)(kcat + row * 576 + l * 8) = o;
  if (l < 32) {
    int p = l;
    int sidx = (int)(row & 2047);
    long base = row * 576 + 512 + 2 * p;
    float re = b2f(kvb[base]), im = b2f(kvb[base + 1]);
    float c = fc[sidx * 32 + p], sn = fs[sidx * 32 + p];
    kcat[base] = f2b(re * c - im * sn);
    kcat[base + 1] = f2b(re * sn + im * c);
  }
}

// ---------- RoPE for q_pe (grid 8192: one pair per thread) ----------
__global__ __launch_bounds__(256) void k_rope_q(const unsigned short* __restrict__ qfull,
                                                const float* __restrict__ fc,
                                                const float* __restrict__ fs,
                                                unsigned short* __restrict__ qcat) {
  long i = (long)blockIdx.x * 256 + threadIdx.x;  // < 2*2048*16*32 = 2097152
  int p = (int)(i & 31); long r = i >> 5;
  int h = (int)(r & 15); r >>= 4;
  int s = (int)(r & 2047); int b = (int)(r >> 11);
  const unsigned short* src = qfull + ((long)(b * 2048 + s)) * 3072 + h * 192 + 128 + 2 * p;
  float re = b2f(src[0]), im = b2f(src[1]);
  float c = fc[s * 32 + p], sn = fs[s * 32 + p];
  unsigned short* dst = qcat + ((long)((b * 16 + h) * 2048 + s)) * 576 + 512 + 2 * p;
  dst[0] = f2b(re * c - im * sn);
  dst[1] = f2b(re * sn + im * c);
}

// ---------- flash attention (Design H13: dbuf + 2-barrier schedule; best config) ----------
// K tile [32 t][576 c] SUBTILED in LDS (sub=(c>>4)*8+(t>>2), elem (t&3)*16+(c&15));
// one copy serves QK A-frags (16B reads) AND PV V^T frags (ds_read_b64_tr_b16).
// Double-buffered; 2 barriers/tile:
//   vmcnt(0) [stage(i) drained, issued during PV(i-1)] -> barrier A -> QK(cur) ->
//   softmax/sP -> barrier B -> issue STAGE(i+1 -> cur^1) -> PV(cur).
// 78KB LDS, (256,2): 128 arch VGPR + 128 acc AGPR = 256/wave -> 2 blocks/CU ceiling.
// (QK chain-splitting regressed twice (R10,R17); single 18-deep chain per tf is best.)
__global__ __launch_bounds__(256, 2) void k_attn(
    const unsigned short* __restrict__ qcat,   // [B*H][2048][576]
    const unsigned short* __restrict__ kcat,   // [B][2048][576]
    unsigned short* __restrict__ ctx,          // [B*H][2048][512]
    const int* __restrict__ spp) {
  __shared__ __align__(16) char smem[78336];
  // [0,73728) sK dbuf | [73728,77824) sP | [77824,78080) sAl | [78080,78096) sNeed
  const int id = blockIdx.x;
  const int rr = id & 7;                       // XCD slot (HW round-robins id%8)
  const int b = rr >> 2;                       // b=0 -> XCD 0-3, b=1 -> XCD 4-7
  const int local = (id >> 3) * 4 + (rr & 3);  // 0..511 within batch class
  const int qb = 31 - (local >> 4);            // LPT: largest blocks first
  const int h = local & 15;
  const int t = threadIdx.x, w = t >> 6, l = t & 63;
  const int lq = l & 15, hh = l >> 4;
  const int sp = spp[0];
  const long bh = (long)(b * 16 + h);
  const long qrow0 = bh * 2048 + qb * 64 + w * 16;
  const float scale = 0.07216878364870323f;    // 1/sqrt(192)

  // Q resident in B-frag layout
  bf16x8 qf[18];
  #pragma unroll
  for (int kk = 0; kk < 18; ++kk)
    qf[kk] = *(const bf16x8*)&qcat[(qrow0 + lq) * 576 + kk * 32 + hh * 8];

  f32x4 acc[8][4];   // D[c][q]: c = w*128 + cb*16 + 4*hh + r ; q = q2*16 + lq
  #pragma unroll
  for (int i = 0; i < 8; ++i)
    #pragma unroll
    for (int j = 0; j < 4; ++j) acc[i][j] = (f32x4){0.f, 0.f, 0.f, 0.f};
  float mrun = -1e30f, lrun = 0.f;
  const int qg = qb * 64 + w * 16 + lq + sp;
  int tmax = qb * 64 + 63 + sp; if (tmax > 2047) tmax = 2047;

  const unsigned short* kbase = kcat + (long)b * 2048 * 576;

  // stage K tile t0 into buffer bi, subtiled layout; chunk c (16B) -> LDS linear c*16
  auto STAGE = [&](int bi, int t0) {
    char* dK = smem + bi * 36864;
    #pragma unroll
    for (int cc = 0; cc < 9; ++cc) {
      int c = t + cc * 256;                    // 0..2303
      int tt = ((c >> 3) & 7) * 4 + ((c >> 1) & 3);
      int gc = (c >> 6) * 16 + (c & 1) * 8;
      gload16(kbase + (long)(t0 + tt) * 576 + gc, dK + c * 16);
    }
  };

  STAGE(0, 0);
  int cur = 0;
  unsigned short* sP = (unsigned short*)(smem + 73728);
  float* sAl = (float*)(smem + 77824);
  int* sNeed = (int*)(smem + 78080);
  const int qrow = w * 16 + lq;                // block-local q (0..63)
  const int xq = ((qrow >> 1) & 3) << 4;
  const int vcol = (hh * 16) ^ (((lq >> 1) & 3) << 4);   // sP read col
  // QK per-lane base byte offset within K tile (subtiled addressing)
  const int kq = ((lq >> 2) << 7) + ((lq & 3) << 5) + ((hh & 1) << 4) + ((hh >> 1) << 10);

  for (int t0 = 0; t0 <= tmax; t0 += 32) {
    // stage(t0) was issued during PV of the previous tile (or pre-loop) -> drain
    asm volatile("s_waitcnt vmcnt(0)" ::: "memory");
    __builtin_amdgcn_sched_barrier(0);
    __builtin_amdgcn_s_barrier();              // A: buffer `cur` staged; prev reads done
    __builtin_amdgcn_sched_barrier(0);

    // ---- QK^T (swapped): scores^T[t][q]
    const char* sKc = smem + cur * 36864;
    f32x4 sc[2];
    sc[0] = (f32x4){0.f,0.f,0.f,0.f}; sc[1] = (f32x4){0.f,0.f,0.f,0.f};
    __builtin_amdgcn_s_setprio(1);
    #pragma unroll
    for (int tf = 0; tf < 2; ++tf) {
      const char* rb = sKc + kq + tf * 512;
      #pragma unroll
      for (int kk = 0; kk < 18; ++kk) {
        bf16x8 kf = *(const bf16x8*)(rb + kk * 2048);
        sc[tf] = __builtin_amdgcn_mfma_f32_16x16x32_bf16(kf, qf[kk], sc[tf], 0, 0, 0);
      }
    }
    __builtin_amdgcn_s_setprio(0);

    // ---- softmax (lane-local per q) with defer-max
    float v[2][4];
    float mt = -1e30f;
    #pragma unroll
    for (int tf = 0; tf < 2; ++tf)
      #pragma unroll
      for (int r = 0; r < 4; ++r) {
        int tg = t0 + tf * 16 + 4 * hh + r;
        v[tf][r] = (tg <= qg) ? sc[tf][r] * scale : -1e30f;
        mt = fmaxf(mt, v[tf][r]);
      }
    mt = fmaxf(mt, __shfl_xor(mt, 16));
    mt = fmaxf(mt, __shfl_xor(mt, 32));
    float al = 1.f;
    unsigned long long needb = __ballot(mt > mrun + 8.f);
    if (needb) {
      float mn = fmaxf(mrun, mt);
      al = __expf(mrun - mn);
      mrun = mn;
      lrun *= al;
    }
    float sr = 0.f;
    #pragma unroll
    for (int tf = 0; tf < 2; ++tf) {
      ushort4 pk;
      float e0 = __expf(v[tf][0] - mrun);
      float e1 = __expf(v[tf][1] - mrun);
      float e2 = __expf(v[tf][2] - mrun);
      float e3 = __expf(v[tf][3] - mrun);
      sr += (e0 + e1) + (e2 + e3);
      pk.x = f2b(e0); pk.y = f2b(e1); pk.z = f2b(e2); pk.w = f2b(e3);
      *(ushort4*)((char*)sP + qrow * 64 + ((32 * tf + 8 * hh) ^ xq)) = pk;
    }
    sr += __shfl_xor(sr, 16);
    sr += __shfl_xor(sr, 32);
    lrun += sr;
    if (l < 16) sAl[w * 16 + l] = al;
    if (l == 0) sNeed[w] = needb ? 1 : 0;
    asm volatile("s_waitcnt lgkmcnt(0)" ::: "memory");
    __builtin_amdgcn_sched_barrier(0);
    __builtin_amdgcn_s_barrier();              // B: sP / sAl / sNeed visible
    __builtin_amdgcn_sched_barrier(0);

    // ---- issue next-tile prefetch NOW (flies during PV); safe per barrier A
    if (t0 + 32 <= tmax) STAGE(cur ^ 1, t0 + 32);
    __builtin_amdgcn_sched_barrier(0);

    // ---- rescale (block-uniform, usually skipped) + PV via tr-reads
    int needAny = sNeed[0] | sNeed[1] | sNeed[2] | sNeed[3];
    if (needAny) {
      float a4[4];
      #pragma unroll
      for (int q2 = 0; q2 < 4; ++q2) a4[q2] = sAl[q2 * 16 + lq];
      #pragma unroll
      for (int cb = 0; cb < 8; ++cb)
        #pragma unroll
        for (int q2 = 0; q2 < 4; ++q2) acc[cb][q2] *= a4[q2];
    }
    bf16x8 pf0 = *(const bf16x8*)((char*)sP + (0 * 16 + lq) * 64 + vcol);
    bf16x8 pf1 = *(const bf16x8*)((char*)sP + (1 * 16 + lq) * 64 + vcol);
    bf16x8 pf2 = *(const bf16x8*)((char*)sP + (2 * 16 + lq) * 64 + vcol);
    bf16x8 pf3 = *(const bf16x8*)((char*)sP + (3 * 16 + lq) * 64 + vcol);
    __builtin_amdgcn_sched_barrier(0);         // pin pf issue before tr-reads (count!)
    AS3c* vp3 = (AS3c*)(smem + cur * 36864 + (w * 8192) + hh * 256 + lq * 8);
    u32x2 A0, A1, B0, B1, C0, C1, D0, D1;
    #define TRR2(d0, d1, CB) do { \
      d0 = tr_read<(CB) * 1024>(vp3); \
      d1 = tr_read<(CB) * 1024 + 128>(vp3); } while (0)
    #define PVC(CB, E0, E1) do { \
      bf16x8 vf = mk8(E0, E1); \
      acc[CB][0] = __builtin_amdgcn_mfma_f32_16x16x32_bf16(vf, pf0, acc[CB][0], 0, 0, 0); \
      acc[CB][1] = __builtin_amdgcn_mfma_f32_16x16x32_bf16(vf, pf1, acc[CB][1], 0, 0, 0); \
      acc[CB][2] = __builtin_amdgcn_mfma_f32_16x16x32_bf16(vf, pf2, acc[CB][2], 0, 0, 0); \
      acc[CB][3] = __builtin_amdgcn_mfma_f32_16x16x32_bf16(vf, pf3, acc[CB][3], 0, 0, 0); } while (0)
    TRR2(A0, A1, 0); TRR2(B0, B1, 1);
    TRR2(C0, C1, 2); TRR2(D0, D1, 3);
    asm volatile("s_waitcnt lgkmcnt(4)" ::: "memory");   // pf + cb0,1 ready
    __builtin_amdgcn_sched_barrier(0);
    __builtin_amdgcn_s_setprio(1);
    PVC(0, A0, A1); PVC(1, B0, B1);
    __builtin_amdgcn_s_setprio(0);
    TRR2(A0, A1, 4); TRR2(B0, B1, 5);
    asm volatile("s_waitcnt lgkmcnt(4)" ::: "memory");   // cb2,3 ready
    __builtin_amdgcn_sched_barrier(0);
    __builtin_amdgcn_s_setprio(1);
    PVC(2, C0, C1); PVC(3, D0, D1);
    __builtin_amdgcn_s_setprio(0);
    TRR2(C0, C1, 6); TRR2(D0, D1, 7);
    asm volatile("s_waitcnt lgkmcnt(4)" ::: "memory");   // cb4,5 ready
    __builtin_amdgcn_sched_barrier(0);
    __builtin_amdgcn_s_setprio(1);
    PVC(4, A0, A1); PVC(5, B0, B1);
    __builtin_amdgcn_s_setprio(0);
    asm volatile("s_waitcnt lgkmcnt(0)" ::: "memory");   // cb6,7 ready
    __builtin_amdgcn_sched_barrier(0);
    __builtin_amdgcn_s_setprio(1);
    PVC(6, C0, C1); PVC(7, D0, D1);
    __builtin_amdgcn_s_setprio(0);
    #undef TRR2
    #undef PVC
    __builtin_amdgcn_sched_barrier(0);
    cur ^= 1;
  }

  // ---- epilogue: 1/l scaling + LDS transpose to coalesced ctx store
  if (l < 16) sAl[w * 16 + l] = lrun;
  __syncthreads();
  float linv[4];
  #pragma unroll
  for (int q2 = 0; q2 < 4; ++q2) linv[q2] = 1.0f / sAl[q2 * 16 + lq];
  unsigned short* eb = (unsigned short*)smem;   // [64 q][528]
  #pragma unroll
  for (int cb = 0; cb < 8; ++cb) {
    const int c0 = w * 128 + cb * 16 + hh * 4;
    #pragma unroll
    for (int q2 = 0; q2 < 4; ++q2) {
      f32x4 a = acc[cb][q2];
      ushort4 o;
      o.x = f2b(a[0] * linv[q2]); o.y = f2b(a[1] * linv[q2]);
      o.z = f2b(a[2] * linv[q2]); o.w = f2b(a[3] * linv[q2]);
      *(ushort4*)&eb[(q2 * 16 + lq) * 528 + c0] = o;
    }
  }
  __syncthreads();
  unsigned short* Co = ctx + (bh * 2048 + qb * 64) * 512;
  #pragma unroll
  for (int i = 0; i < 16; ++i) {
    int id2 = t + i * 256;                     // 0..4095 chunks of 8 elems
    int row = id2 >> 6, col = (id2 & 63) * 8;
    *(u16x8*)&Co[(long)row * 512 + col] = *(const u16x8*)&eb[row * 528 + col];
  }
}

// ---------- host launch ----------
extern "C" void kernel_launch(void* const* d_in, const int* in_sizes, int n_in,
                              void* d_out, int out_size, void* d_ws, size_t ws_size,
                              hipStream_t stream) {
  const float* x      = (const float*)d_in[0];
  const int*   sp     = (const int*)d_in[1];
  const float* fcos   = (const float*)d_in[2];
  const float* fsin   = (const float*)d_in[3];
  const float* wq_w   = (const float*)d_in[4];
  const float* wq_b   = (const float*)d_in[5];
  const float* wkva_w = (const float*)d_in[6];
  const float* wkva_b = (const float*)d_in[7];
  const float* lng    = (const float*)d_in[8];
  const float* lnb    = (const float*)d_in[9];
  const float* wkvb_w = (const float*)d_in[10];
  const float* wo_w   = (const float*)d_in[11];
  const float* wo_b   = (const float*)d_in[12];
  float* out = (float*)d_out;

  if (ws_size < 171180032) return;

  char* ws = (char*)d_ws;
  unsigned short* xb     = (unsigned short*)(ws + 0);
  unsigned short* wqbf   = (unsigned short*)(ws + 16777216);
  unsigned short* qfull  = (unsigned short*)(ws + 29360128);
  unsigned short* ctx    = (unsigned short*)(ws + 0);
  unsigned short* wkvabf = (unsigned short*)(ws + 67108864);
  unsigned short* wkvbkT = (unsigned short*)(ws + 69468160);
  unsigned short* wkvbv  = (unsigned short*)(ws + 71565312);
  unsigned short* wobf   = (unsigned short*)(ws + 73662464);
  unsigned short* kvbf   = (unsigned short*)(ws + 82051072);
  unsigned short* kcat   = (unsigned short*)(ws + 86769664);
  unsigned short* qcat   = (unsigned short*)(ws + 95682560);
  unsigned short* outh   = qcat;

  k_cast<<<8192, 256, 0, stream>>>(x, xb, 8388608L);
  k_cast<<<6144, 256, 0, stream>>>(wq_w, wqbf, 6291456L);
  k_cast<<<1152, 256, 0, stream>>>(wkva_w, wkvabf, 1179648L);
  k_cast<<<4096, 256, 0, stream>>>(wo_w, wobf, 4194304L);
  k_prep_wkvb<<<4096, 256, 0, stream>>>(wkvb_w, wkvbkT, wkvbv);

  k_gemm_bt<0, 1><<<dim3(24, 32, 1), 256, 0, stream>>>(
      xb, 2048, 0, 0, wqbf, 2048, 0, 0, qfull, 3072, 0, 0, wq_b, 4096, 3072, 2048, 1);
  k_gemm_bt<0, 1><<<dim3(5, 32, 1), 256, 0, stream>>>(
      xb, 2048, 0, 0, wkvabf, 2048, 0, 0, kvbf, 576, 0, 0, wkva_b, 4096, 576, 2048, 1);

  k_ln_rope<<<1024, 256, 0, stream>>>(kvbf, lng, lnb, fcos, fsin, kcat);
  k_rope_q<<<8192, 256, 0, stream>>>(qfull, fcos, fsin, qcat);

  k_gemm_bt<0, 0><<<dim3(4, 16, 32), 256, 0, stream>>>(
      qfull, 3072, (long)2048 * 3072, 192,
      wkvbkT, 128, 0, (long)512 * 128,
      qcat, 576, (long)16 * 2048 * 576, (long)2048 * 576,
      nullptr, 2048, 512, 128, 16);

  k_attn<<<dim3(1024, 1, 1), 256, 0, stream>>>(qcat, kcat, ctx, sp);

  k_gemm_bt<0, 0><<<dim3(1, 16, 32), 256, 0, stream>>>(
      ctx, 512, (long)16 * 2048 * 512, (long)2048 * 512,
      wkvbv, 512, 0, (long)128 * 512,
      outh, 2048, (long)2048 * 2048, 128,
      nullptr, 2048, 128, 512, 16);

  k_gemm_bt<1, 1><<<dim3(16, 32, 1), 256, 0, stream>>>(
      outh, 2048, 0, 0, wobf, 2048, 0, 0, out, 2048, 0, 0, wo_b, 4096, 2048, 2048, 1);
}

// Round 19
// 601.782 us; speedup vs baseline: 1.0360x; 1.0065x over previous
//
#include <hip/hip_runtime.h>
#include <stdint.h>

// ---------- common types / helpers ----------
typedef __attribute__((ext_vector_type(8))) __bf16 bf16x8;   // MFMA A/B frag (4 VGPR)
typedef __attribute__((ext_vector_type(4))) float  f32x4;    // MFMA C/D frag
typedef __attribute__((ext_vector_type(8))) unsigned short u16x8;
typedef __attribute__((ext_vector_type(2))) unsigned int u32x2;
typedef __attribute__((ext_vector_type(4))) unsigned int u32x4;

typedef __attribute__((address_space(1))) void AS1void;
typedef __attribute__((address_space(3))) void AS3void;
typedef __attribute__((address_space(3))) const unsigned char AS3c;

__device__ __forceinline__ float b2f(unsigned short u) {
  unsigned x = ((unsigned)u) << 16; float f; __builtin_memcpy(&f, &x, 4); return f;
}
__device__ __forceinline__ unsigned short f2b(float f) {
  unsigned x; __builtin_memcpy(&x, &f, 4);
  unsigned r = (x + 0x7fffu + ((x >> 16) & 1u)) >> 16;
  return (unsigned short)r;
}
// async global->LDS, 16B per lane; LDS dest must be wave-uniform base + lane*16
__device__ __forceinline__ void gload16(const void* g, void* l) {
  __builtin_amdgcn_global_load_lds((AS1void*)(void*)g, (AS3void*)l, 16, 0, 0);
}
__device__ __forceinline__ bf16x8 mk8(u32x2 a, u32x2 b) {
  u32x4 t; t[0] = a[0]; t[1] = a[1]; t[2] = b[0]; t[3] = b[1];
  bf16x8 r; __builtin_memcpy(&r, &t, 16); return r;
}
// ds_read_b64_tr_b16: HW 4x16 bf16 transpose within each 16-lane group [m156/m162].
template<int OFF>
__device__ __forceinline__ u32x2 tr_read(AS3c* vp) {
  u32x2 r;
  asm volatile("ds_read_b64_tr_b16 %0, %1 offset:%2"
               : "=&v"(r) : "v"(vp), "n"(OFF));
  return r;
}

// ---------- elementwise cast f32 -> bf16 ----------
__global__ __launch_bounds__(256) void k_cast(const float* __restrict__ in,
                                              unsigned short* __restrict__ out, long n) {
  long i = ((long)blockIdx.x * 256 + threadIdx.x) * 4;
  if (i >= n) return;
  float4 v = *(const float4*)(in + i);
  ushort4 o;
  o.x = f2b(v.x); o.y = f2b(v.y); o.z = f2b(v.z); o.w = f2b(v.w);
  *(ushort4*)(out + i) = o;
}

// ---------- merged weight casts: wq | wkva | wo (segments block-aligned: 1024 elems/block)
__global__ __launch_bounds__(256) void k_cast3(const float* __restrict__ in1, unsigned short* __restrict__ o1, long n1,
                                               const float* __restrict__ in2, unsigned short* __restrict__ o2, long n2,
                                               const float* __restrict__ in3, unsigned short* __restrict__ o3) {
  long i = ((long)blockIdx.x * 256 + threadIdx.x) * 4;
  const float* in; unsigned short* out;
  if (i < n1)            { in = in1 + i;            out = o1 + i; }
  else if (i < n1 + n2)  { in = in2 + (i - n1);     out = o2 + (i - n1); }
  else                   { in = in3 + (i - n1 - n2); out = o3 + (i - n1 - n2); }
  float4 v = *(const float4*)in;
  ushort4 o;
  o.x = f2b(v.x); o.y = f2b(v.y); o.z = f2b(v.z); o.w = f2b(v.w);
  *(ushort4*)out = o;
}

// ---------- wkv_b prep ----------
__global__ __launch_bounds__(256) void k_prep_wkvb(const float* __restrict__ wkvb,
                                                   unsigned short* __restrict__ kT,
                                                   unsigned short* __restrict__ vv) {
  long i = (long)blockIdx.x * 256 + threadIdx.x;   // < 16*512*128 = 1048576
  {
    int d = (int)(i & 127); long r = i >> 7; int c = (int)(r & 511); int h = (int)(r >> 9);
    kT[i] = f2b(wkvb[((long)(h * 256 + d)) * 512 + c]);
  }
  {
    int c = (int)(i & 511); long r = i >> 9; int d = (int)(r & 127); int h = (int)(r >> 7);
    vv[i] = f2b(wkvb[((long)(h * 256 + 128 + d)) * 512 + c]);
  }
}

// ---------- generic BT-form GEMM: C[M,N] = A[M,K] @ B[N,K]^T (+bias) ----------
// Bijective XCD swizzle (m204) on the xy grid for per-XCD L2 weight locality.
template<int OUTF32, int BIAS>
__global__ __launch_bounds__(256, 4) void k_gemm_bt(
    const unsigned short* __restrict__ A, long lda, long aSb, long aSh,
    const unsigned short* __restrict__ B, long ldb, long bSb, long bSh,
    void* __restrict__ Cp, long ldc, long cSb, long cSh,
    const float* __restrict__ bias,
    int M, int N, int K, int zH) {
  __shared__ __align__(16) unsigned short sA[128 * 32];
  __shared__ __align__(16) unsigned short sB[128 * 32];
  const int z = blockIdx.z, zb = z / zH, zh = z % zH;
  const unsigned short* Ab = A + zb * aSb + zh * aSh;
  const unsigned short* Bb = B + zb * bSb + zh * bSh;
  const long cOff = (long)zb * cSb + (long)zh * cSh;
  const int nwg = gridDim.x * gridDim.y;
  int flat = blockIdx.y * gridDim.x + blockIdx.x;
  {
    int q = nwg >> 3, r = nwg & 7;
    int xcd = flat & 7, j = flat >> 3;
    flat = (xcd < r ? xcd * (q + 1) : r * (q + 1) + (xcd - r) * q) + j;
  }
  const int n0 = (flat % gridDim.x) * 128, m0 = (flat / gridDim.x) * 128;
  const int t = threadIdx.x, w = t >> 6, l = t & 63;
  const int wr = (w >> 1) * 64, wc = (w & 1) * 64;
  const int lr = l & 15, lg = l >> 4;
  f32x4 acc[4][4] = {};
  for (int k0 = 0; k0 < K; k0 += 32) {
    #pragma unroll
    for (int cc = 0; cc < 2; ++cc) {
      int c = t + cc * 256;
      int row = c >> 2, col = (c & 3) * 8;
      int ar = m0 + row; ar = ar < M ? ar : M - 1;
      int br = n0 + row; br = br < N ? br : N - 1;
      gload16(Ab + (long)ar * lda + k0 + col, (char*)sA + c * 16);
      gload16(Bb + (long)br * ldb + k0 + col, (char*)sB + c * 16);
    }
    __syncthreads();
    bf16x8 af[4], bf[4];
    #pragma unroll
    for (int i = 0; i < 4; ++i) af[i] = *(const bf16x8*)&sA[(wr + i * 16 + lr) * 32 + lg * 8];
    #pragma unroll
    for (int j = 0; j < 4; ++j) bf[j] = *(const bf16x8*)&sB[(wc + j * 16 + lr) * 32 + lg * 8];
    #pragma unroll
    for (int i = 0; i < 4; ++i)
      #pragma unroll
      for (int j = 0; j < 4; ++j)
        acc[i][j] = __builtin_amdgcn_mfma_f32_16x16x32_bf16(af[i], bf[j], acc[i][j], 0, 0, 0);
    __syncthreads();
  }
  #pragma unroll
  for (int i = 0; i < 4; ++i) {
    #pragma unroll
    for (int r = 0; r < 4; ++r) {
      int row = m0 + wr + i * 16 + lg * 4 + r;
      if (row >= M) continue;
      #pragma unroll
      for (int j = 0; j < 4; ++j) {
        int col = n0 + wc + j * 16 + lr;
        if (col >= N) continue;
        float v = acc[i][j][r];
        if (BIAS) v += bias[col];
        if (OUTF32) ((float*)Cp)[cOff + (long)row * ldc + col] = v;
        else ((unsigned short*)Cp)[cOff + (long)row * ldc + col] = f2b(v);
      }
    }
  }
}

// ---------- fused LayerNorm (cols 0..511) + RoPE k_pe (cols 512..575) ----------
__global__ __launch_bounds__(256) void k_ln_rope(const unsigned short* __restrict__ kvb,
                                                 const float* __restrict__ g,
                                                 const float* __restrict__ be,
                                                 const float* __restrict__ fc,
                                                 const float* __restrict__ fs,
                                                 unsigned short* __restrict__ kcat) {
  const int w = threadIdx.x >> 6, l = threadIdx.x & 63;
  const long row = (long)blockIdx.x * 4 + w;       // 0..4095
  const unsigned short* src = kvb + row * 576 + l * 8;
  u16x8 v = *(const u16x8*)src;
  float f[8]; float s = 0.f, s2 = 0.f;
  #pragma unroll
  for (int j = 0; j < 8; ++j) { f[j] = b2f(v[j]); s += f[j]; s2 += f[j] * f[j]; }
  #pragma unroll
  for (int m = 1; m < 64; m <<= 1) { s += __shfl_xor(s, m); s2 += __shfl_xor(s2, m); }
  float mu = s * (1.f / 512.f);
  float var = s2 * (1.f / 512.f) - mu * mu;
  float rs = rsqrtf(var + 1e-5f);
  u16x8 o;
  #pragma unroll
  for (int j = 0; j < 8; ++j) {
    int c = l * 8 + j;
    o[j] = f2b((f[j] - mu) * rs * g[c] + be[c]);
  }
  *(u16x8*)(kcat + row * 576 + l * 8) = o;
  if (l < 32) {
    int p = l;
    int sidx = (int)(row & 2047);
    long base = row * 576 + 512 + 2 * p;
    float re = b2f(kvb[base]), im = b2f(kvb[base + 1]);
    float c = fc[sidx * 32 + p], sn = fs[sidx * 32 + p];
    kcat[base] = f2b(re * c - im * sn);
    kcat[base + 1] = f2b(re * sn + im * c);
  }
}

// ---------- RoPE for q_pe (grid 8192: one pair per thread) ----------
__global__ __launch_bounds__(256) void k_rope_q(const unsigned short* __restrict__ qfull,
                                                const float* __restrict__ fc,
                                                const float* __restrict__ fs,
                                                unsigned short* __restrict__ qcat) {
  long i = (long)blockIdx.x * 256 + threadIdx.x;  // < 2*2048*16*32 = 2097152
  int p = (int)(i & 31); long r = i >> 5;
  int h = (int)(r & 15); r >>= 4;
  int s = (int)(r & 2047); int b = (int)(r >> 11);
  const unsigned short* src = qfull + ((long)(b * 2048 + s)) * 3072 + h * 192 + 128 + 2 * p;
  float re = b2f(src[0]), im = b2f(src[1]);
  float c = fc[s * 32 + p], sn = fs[s * 32 + p];
  unsigned short* dst = qcat + ((long)((b * 16 + h) * 2048 + s)) * 576 + 512 + 2 * p;
  dst[0] = f2b(re * c - im * sn);
  dst[1] = f2b(re * sn + im * c);
}

// ---------- flash attention (Design H13: dbuf + 2-barrier schedule; best config) ----------
// K tile [32 t][576 c] SUBTILED in LDS (sub=(c>>4)*8+(t>>2), elem (t&3)*16+(c&15));
// one copy serves QK A-frags (16B reads) AND PV V^T frags (ds_read_b64_tr_b16).
// Double-buffered; 2 barriers/tile:
//   vmcnt(0) [stage(i) drained, issued during PV(i-1)] -> barrier A -> QK(cur) ->
//   softmax/sP -> barrier B -> issue STAGE(i+1 -> cur^1) -> PV(cur).
// 78KB LDS, (256,2): 128 arch VGPR + 128 acc AGPR = 256/wave -> 2 blocks/CU ceiling.
// (QK chain-splitting regressed twice (R10,R17); single 18-deep chain per tf is best.)
__global__ __launch_bounds__(256, 2) void k_attn(
    const unsigned short* __restrict__ qcat,   // [B*H][2048][576]
    const unsigned short* __restrict__ kcat,   // [B][2048][576]
    unsigned short* __restrict__ ctx,          // [B*H][2048][512]
    const int* __restrict__ spp) {
  __shared__ __align__(16) char smem[78336];
  // [0,73728) sK dbuf | [73728,77824) sP | [77824,78080) sAl | [78080,78096) sNeed
  const int id = blockIdx.x;
  const int rr = id & 7;                       // XCD slot (HW round-robins id%8)
  const int b = rr >> 2;                       // b=0 -> XCD 0-3, b=1 -> XCD 4-7
  const int local = (id >> 3) * 4 + (rr & 3);  // 0..511 within batch class
  const int qb = 31 - (local >> 4);            // LPT: largest blocks first
  const int h = local & 15;
  const int t = threadIdx.x, w = t >> 6, l = t & 63;
  const int lq = l & 15, hh = l >> 4;
  const int sp = spp[0];
  const long bh = (long)(b * 16 + h);
  const long qrow0 = bh * 2048 + qb * 64 + w * 16;
  const float scale = 0.07216878364870323f;    // 1/sqrt(192)

  // Q resident in B-frag layout
  bf16x8 qf[18];
  #pragma unroll
  for (int kk = 0; kk < 18; ++kk)
    qf[kk] = *(const bf16x8*)&qcat[(qrow0 + lq) * 576 + kk * 32 + hh * 8];

  f32x4 acc[8][4];   // D[c][q]: c = w*128 + cb*16 + 4*hh + r ; q = q2*16 + lq
  #pragma unroll
  for (int i = 0; i < 8; ++i)
    #pragma unroll
    for (int j = 0; j < 4; ++j) acc[i][j] = (f32x4){0.f, 0.f, 0.f, 0.f};
  float mrun = -1e30f, lrun = 0.f;
  const int qg = qb * 64 + w * 16 + lq + sp;
  int tmax = qb * 64 + 63 + sp; if (tmax > 2047) tmax = 2047;

  const unsigned short* kbase = kcat + (long)b * 2048 * 576;

  // stage K tile t0 into buffer bi, subtiled layout; chunk c (16B) -> LDS linear c*16
  auto STAGE = [&](int bi, int t0) {
    char* dK = smem + bi * 36864;
    #pragma unroll
    for (int cc = 0; cc < 9; ++cc) {
      int c = t + cc * 256;                    // 0..2303
      int tt = ((c >> 3) & 7) * 4 + ((c >> 1) & 3);
      int gc = (c >> 6) * 16 + (c & 1) * 8;
      gload16(kbase + (long)(t0 + tt) * 576 + gc, dK + c * 16);
    }
  };

  STAGE(0, 0);
  int cur = 0;
  unsigned short* sP = (unsigned short*)(smem + 73728);
  float* sAl = (float*)(smem + 77824);
  int* sNeed = (int*)(smem + 78080);
  const int qrow = w * 16 + lq;                // block-local q (0..63)
  const int xq = ((qrow >> 1) & 3) << 4;
  const int vcol = (hh * 16) ^ (((lq >> 1) & 3) << 4);   // sP read col
  // QK per-lane base byte offset within K tile (subtiled addressing)
  const int kq = ((lq >> 2) << 7) + ((lq & 3) << 5) + ((hh & 1) << 4) + ((hh >> 1) << 10);

  for (int t0 = 0; t0 <= tmax; t0 += 32) {
    // stage(t0) was issued during PV of the previous tile (or pre-loop) -> drain
    asm volatile("s_waitcnt vmcnt(0)" ::: "memory");
    __builtin_amdgcn_sched_barrier(0);
    __builtin_amdgcn_s_barrier();              // A: buffer `cur` staged; prev reads done
    __builtin_amdgcn_sched_barrier(0);

    // ---- QK^T (swapped): scores^T[t][q]
    const char* sKc = smem + cur * 36864;
    f32x4 sc[2];
    sc[0] = (f32x4){0.f,0.f,0.f,0.f}; sc[1] = (f32x4){0.f,0.f,0.f,0.f};
    __builtin_amdgcn_s_setprio(1);
    #pragma unroll
    for (int tf = 0; tf < 2; ++tf) {
      const char* rb = sKc + kq + tf * 512;
      #pragma unroll
      for (int kk = 0; kk < 18; ++kk) {
        bf16x8 kf = *(const bf16x8*)(rb + kk * 2048);
        sc[tf] = __builtin_amdgcn_mfma_f32_16x16x32_bf16(kf, qf[kk], sc[tf], 0, 0, 0);
      }
    }
    __builtin_amdgcn_s_setprio(0);

    // ---- softmax (lane-local per q) with defer-max
    float v[2][4];
    float mt = -1e30f;
    #pragma unroll
    for (int tf = 0; tf < 2; ++tf)
      #pragma unroll
      for (int r = 0; r < 4; ++r) {
        int tg = t0 + tf * 16 + 4 * hh + r;
        v[tf][r] = (tg <= qg) ? sc[tf][r] * scale : -1e30f;
        mt = fmaxf(mt, v[tf][r]);
      }
    mt = fmaxf(mt, __shfl_xor(mt, 16));
    mt = fmaxf(mt, __shfl_xor(mt, 32));
    float al = 1.f;
    unsigned long long needb = __ballot(mt > mrun + 8.f);
    if (needb) {
      float mn = fmaxf(mrun, mt);
      al = __expf(mrun - mn);
      mrun = mn;
      lrun *= al;
    }
    float sr = 0.f;
    #pragma unroll
    for (int tf = 0; tf < 2; ++tf) {
      ushort4 pk;
      float e0 = __expf(v[tf][0] - mrun);
      float e1 = __expf(v[tf][1] - mrun);
      float e2 = __expf(v[tf][2] - mrun);
      float e3 = __expf(v[tf][3] - mrun);
      sr += (e0 + e1) + (e2 + e3);
      pk.x = f2b(e0); pk.y = f2b(e1); pk.z = f2b(e2); pk.w = f2b(e3);
      *(ushort4*)((char*)sP + qrow * 64 + ((32 * tf + 8 * hh) ^ xq)) = pk;
    }
    sr += __shfl_xor(sr, 16);
    sr += __shfl_xor(sr, 32);
    lrun += sr;
    if (l < 16) sAl[w * 16 + l] = al;
    if (l == 0) sNeed[w] = needb ? 1 : 0;
    asm volatile("s_waitcnt lgkmcnt(0)" ::: "memory");
    __builtin_amdgcn_sched_barrier(0);
    __builtin_amdgcn_s_barrier();              // B: sP / sAl / sNeed visible
    __builtin_amdgcn_sched_barrier(0);

    // ---- issue next-tile prefetch NOW (flies during PV); safe per barrier A
    if (t0 + 32 <= tmax) STAGE(cur ^ 1, t0 + 32);
    __builtin_amdgcn_sched_barrier(0);

    // ---- rescale (block-uniform, usually skipped) + PV via tr-reads
    int needAny = sNeed[0] | sNeed[1] | sNeed[2] | sNeed[3];
    if (needAny) {
      float a4[4];
      #pragma unroll
      for (int q2 = 0; q2 < 4; ++q2) a4[q2] = sAl[q2 * 16 + lq];
      #pragma unroll
      for (int cb = 0; cb < 8; ++cb)
        #pragma unroll
        for (int q2 = 0; q2 < 4; ++q2) acc[cb][q2] *= a4[q2];
    }
    bf16x8 pf0 = *(const bf16x8*)((char*)sP + (0 * 16 + lq) * 64 + vcol);
    bf16x8 pf1 = *(const bf16x8*)((char*)sP + (1 * 16 + lq) * 64 + vcol);
    bf16x8 pf2 = *(const bf16x8*)((char*)sP + (2 * 16 + lq) * 64 + vcol);
    bf16x8 pf3 = *(const bf16x8*)((char*)sP + (3 * 16 + lq) * 64 + vcol);
    __builtin_amdgcn_sched_barrier(0);         // pin pf issue before tr-reads (count!)
    AS3c* vp3 = (AS3c*)(smem + cur * 36864 + (w * 8192) + hh * 256 + lq * 8);
    u32x2 A0, A1, B0, B1, C0, C1, D0, D1;
    #define TRR2(d0, d1, CB) do { \
      d0 = tr_read<(CB) * 1024>(vp3); \
      d1 = tr_read<(CB) * 1024 + 128>(vp3); } while (0)
    #define PVC(CB, E0, E1) do { \
      bf16x8 vf = mk8(E0, E1); \
      acc[CB][0] = __builtin_amdgcn_mfma_f32_16x16x32_bf16(vf, pf0, acc[CB][0], 0, 0, 0); \
      acc[CB][1] = __builtin_amdgcn_mfma_f32_16x16x32_bf16(vf, pf1, acc[CB][1], 0, 0, 0); \
      acc[CB][2] = __builtin_amdgcn_mfma_f32_16x16x32_bf16(vf, pf2, acc[CB][2], 0, 0, 0); \
      acc[CB][3] = __builtin_amdgcn_mfma_f32_16x16x32_bf16(vf, pf3, acc[CB][3], 0, 0, 0); } while (0)
    TRR2(A0, A1, 0); TRR2(B0, B1, 1);
    TRR2(C0, C1, 2); TRR2(D0, D1, 3);
    asm volatile("s_waitcnt lgkmcnt(4)" ::: "memory");   // pf + cb0,1 ready
    __builtin_amdgcn_sched_barrier(0);
    __builtin_amdgcn_s_setprio(1);
    PVC(0, A0, A1); PVC(1, B0, B1);
    __builtin_amdgcn_s_setprio(0);
    TRR2(A0, A1, 4); TRR2(B0, B1, 5);
    asm volatile("s_waitcnt lgkmcnt(4)" ::: "memory");   // cb2,3 ready
    __builtin_amdgcn_sched_barrier(0);
    __builtin_amdgcn_s_setprio(1);
    PVC(2, C0, C1); PVC(3, D0, D1);
    __builtin_amdgcn_s_setprio(0);
    TRR2(C0, C1, 6); TRR2(D0, D1, 7);
    asm volatile("s_waitcnt lgkmcnt(4)" ::: "memory");   // cb4,5 ready
    __builtin_amdgcn_sched_barrier(0);
    __builtin_amdgcn_s_setprio(1);
    PVC(4, A0, A1); PVC(5, B0, B1);
    __builtin_amdgcn_s_setprio(0);
    asm volatile("s_waitcnt lgkmcnt(0)" ::: "memory");   // cb6,7 ready
    __builtin_amdgcn_sched_barrier(0);
    __builtin_amdgcn_s_setprio(1);
    PVC(6, C0, C1); PVC(7, D0, D1);
    __builtin_amdgcn_s_setprio(0);
    #undef TRR2
    #undef PVC
    __builtin_amdgcn_sched_barrier(0);
    cur ^= 1;
  }

  // ---- epilogue: 1/l scaling + LDS transpose to coalesced ctx store
  if (l < 16) sAl[w * 16 + l] = lrun;
  __syncthreads();
  float linv[4];
  #pragma unroll
  for (int q2 = 0; q2 < 4; ++q2) linv[q2] = 1.0f / sAl[q2 * 16 + lq];
  unsigned short* eb = (unsigned short*)smem;   // [64 q][528]
  #pragma unroll
  for (int cb = 0; cb < 8; ++cb) {
    const int c0 = w * 128 + cb * 16 + hh * 4;
    #pragma unroll
    for (int q2 = 0; q2 < 4; ++q2) {
      f32x4 a = acc[cb][q2];
      ushort4 o;
      o.x = f2b(a[0] * linv[q2]); o.y = f2b(a[1] * linv[q2]);
      o.z = f2b(a[2] * linv[q2]); o.w = f2b(a[3] * linv[q2]);
      *(ushort4*)&eb[(q2 * 16 + lq) * 528 + c0] = o;
    }
  }
  __syncthreads();
  unsigned short* Co = ctx + (bh * 2048 + qb * 64) * 512;
  #pragma unroll
  for (int i = 0; i < 16; ++i) {
    int id2 = t + i * 256;                     // 0..4095 chunks of 8 elems
    int row = id2 >> 6, col = (id2 & 63) * 8;
    *(u16x8*)&Co[(long)row * 512 + col] = *(const u16x8*)&eb[row * 528 + col];
  }
}

// ---------- host launch ----------
extern "C" void kernel_launch(void* const* d_in, const int* in_sizes, int n_in,
                              void* d_out, int out_size, void* d_ws, size_t ws_size,
                              hipStream_t stream) {
  const float* x      = (const float*)d_in[0];
  const int*   sp     = (const int*)d_in[1];
  const float* fcos   = (const float*)d_in[2];
  const float* fsin   = (const float*)d_in[3];
  const float* wq_w   = (const float*)d_in[4];
  const float* wq_b   = (const float*)d_in[5];
  const float* wkva_w = (const float*)d_in[6];
  const float* wkva_b = (const float*)d_in[7];
  const float* lng    = (const float*)d_in[8];
  const float* lnb    = (const float*)d_in[9];
  const float* wkvb_w = (const float*)d_in[10];
  const float* wo_w   = (const float*)d_in[11];
  const float* wo_b   = (const float*)d_in[12];
  float* out = (float*)d_out;

  if (ws_size < 171180032) return;

  char* ws = (char*)d_ws;
  unsigned short* xb     = (unsigned short*)(ws + 0);
  unsigned short* wqbf   = (unsigned short*)(ws + 16777216);
  unsigned short* qfull  = (unsigned short*)(ws + 29360128);
  unsigned short* ctx    = (unsigned short*)(ws + 0);
  unsigned short* wkvabf = (unsigned short*)(ws + 67108864);
  unsigned short* wkvbkT = (unsigned short*)(ws + 69468160);
  unsigned short* wkvbv  = (unsigned short*)(ws + 71565312);
  unsigned short* wobf   = (unsigned short*)(ws + 73662464);
  unsigned short* kvbf   = (unsigned short*)(ws + 82051072);
  unsigned short* kcat   = (unsigned short*)(ws + 86769664);
  unsigned short* qcat   = (unsigned short*)(ws + 95682560);
  unsigned short* outh   = qcat;

  k_cast<<<8192, 256, 0, stream>>>(x, xb, 8388608L);
  // merged weight casts: 6144 + 1152 + 4096 = 11392 blocks (segments block-aligned)
  k_cast3<<<11392, 256, 0, stream>>>(wq_w, wqbf, 6291456L,
                                     wkva_w, wkvabf, 1179648L,
                                     wo_w, wobf);
  k_prep_wkvb<<<4096, 256, 0, stream>>>(wkvb_w, wkvbkT, wkvbv);

  k_gemm_bt<0, 1><<<dim3(24, 32, 1), 256, 0, stream>>>(
      xb, 2048, 0, 0, wqbf, 2048, 0, 0, qfull, 3072, 0, 0, wq_b, 4096, 3072, 2048, 1);
  k_gemm_bt<0, 1><<<dim3(5, 32, 1), 256, 0, stream>>>(
      xb, 2048, 0, 0, wkvabf, 2048, 0, 0, kvbf, 576, 0, 0, wkva_b, 4096, 576, 2048, 1);

  k_ln_rope<<<1024, 256, 0, stream>>>(kvbf, lng, lnb, fcos, fsin, kcat);
  k_rope_q<<<8192, 256, 0, stream>>>(qfull, fcos, fsin, qcat);

  k_gemm_bt<0, 0><<<dim3(4, 16, 32), 256, 0, stream>>>(
      qfull, 3072, (long)2048 * 3072, 192,
      wkvbkT, 128, 0, (long)512 * 128,
      qcat, 576, (long)16 * 2048 * 576, (long)2048 * 576,
      nullptr, 2048, 512, 128, 16);

  k_attn<<<dim3(1024, 1, 1), 256, 0, stream>>>(qcat, kcat, ctx, sp);

  k_gemm_bt<0, 0><<<dim3(1, 16, 32), 256, 0, stream>>>(
      ctx, 512, (long)16 * 2048 * 512, (long)2048 * 512,
      wkvbv, 512, 0, (long)128 * 512,
      outh, 2048, (long)2048 * 2048, 128,
      nullptr, 2048, 128, 512, 16);

  k_gemm_bt<1, 1><<<dim3(16, 32, 1), 256, 0, stream>>>(
      outh, 2048, 0, 0, wobf, 2048, 0, 0, out, 2048, 0, 0, wo_b, 4096, 2048, 2048, 1);
}